// Round 10
// baseline (1199.110 us; speedup 1.0000x reference)
//
#include <hip/hip_runtime.h>
#include <hip/hip_bf16.h>
#include <math.h>

#define NB    16
#define NPC   4096        // points per cloud
#define MPC   1024        // clusters per cloud
#define PTOT  65536
#define NCLU  16384
#define KNN_  16
#define CIN   64
#define COUT_ 128
#define CAUX_ 32

// out offsets (float elements), outputs concatenated in reference return order
#define OFF_XOUT   0
#define OFF_SUBPOS (NCLU*COUT_)               // 2097152
#define OFF_SUBB   (OFF_SUBPOS + NCLU*3)      // 2146304
#define OFF_AUX    (OFF_SUBB + NCLU)          // 2162688
#define OFF_IDCL   (OFF_AUX + NCLU*CAUX_)     // 2686976

// ws offsets (bytes)
#define WS_H        0
#define WS_CENTERS  (PTOT*COUT_*4)            // h: P x 128 f32
#define WS_STATS    (WS_CENTERS + NCLU*16)    // centers: float4 per cluster
#define WS_NEED     (WS_STATS + 256*4)

// ---- shared-memory overlay for the fused fps/gemm kernel -------------------
// fps view: TWO independent clouds per block (A and B), interleaved chains.
#define SM_LXA   0                      // 4096 f (16384 B)
#define SM_LYA   16384
#define SM_LZA   32768
#define SM_LXB   49152
#define SM_LYB   65536
#define SM_LZB   81920
#define SM_CANDA 98304                  // 2 parity * 32 f64 = 512 B
#define SM_CANDB 98816                  // 512 B
#define SM_CSELA 99328                  // 1024 int = 4096 B
#define SM_CSELB 103424                 // 4096 B -> 107520
// gemm view:
#define SM_XT    0                      // float[64][68] = 17408 B
#define SM_WL    17408                  // float[64][128] = 32768 B -> 50176
#define SM_BS    50176                  // float[128]
#define SM_BQ    50688                  // float[128] -> 51200
#define SM_SIZE  107520

// f64-packed keys: hi32 = f32 bits of d2 (>=0, finite -> positive f64, no NaN),
// lo32 = index payload. Positive doubles order exactly as their u64 bit
// patterns; f64 denormals are never flushed on AMD -> v_max_f64/v_min_f64 is a
// single-instruction lexicographic compare.
__device__ __forceinline__ double dmax(double a, double b) { return __builtin_fmax(a, b); }
__device__ __forceinline__ double dmin(double a, double b) { return __builtin_fmin(a, b); }
__device__ __forceinline__ double pk(float d, int lo) {
  return __hiloint2double(__float_as_int(d), lo);
}
__device__ __forceinline__ int pk_lo(double k) {
  return (int)(unsigned)(__double_as_longlong(k) & 0xFFFFFFFFll);
}

// DPP row_ror:N on an f64 (both 32b halves, same control -> consistent lanes).
template <int CTRL>
__device__ __forceinline__ double dpp64(double v) {
  long long u = __double_as_longlong(v);
  int lo = (int)(unsigned)(u & 0xFFFFFFFFll);
  int hi = (int)(unsigned)((unsigned long long)u >> 32);
  int rlo = __builtin_amdgcn_update_dpp(0, lo, CTRL, 0xf, 0xf, true);
  int rhi = __builtin_amdgcn_update_dpp(0, hi, CTRL, 0xf, 0xf, true);
  return __longlong_as_double(((long long)rhi << 32) | (long long)(unsigned)rlo);
}
#define ROR1 0x121
#define ROR2 0x122
#define ROR4 0x124
#define ROR8 0x128

// full 16-lane-row max via DPP rotate-accumulate (VALU pipe only)
__device__ __forceinline__ double rowmax16(double w) {
  w = dmax(w, dpp64<ROR1>(w));
  w = dmax(w, dpp64<ROR2>(w));
  w = dmax(w, dpp64<ROR4>(w));
  w = dmax(w, dpp64<ROR8>(w));
  return w;
}

// ---------------- FPS block: 2 interleaved clouds, 1 barrier/step -----------
__device__ void fps_block2(char* smem, const float* __restrict__ pos,
                           float4* __restrict__ centers, float* __restrict__ out,
                           int b0)
{
  #pragma clang fp contract(off)
  float* lxA = (float*)(smem + SM_LXA);
  float* lyA = (float*)(smem + SM_LYA);
  float* lzA = (float*)(smem + SM_LZA);
  float* lxB = (float*)(smem + SM_LXB);
  float* lyB = (float*)(smem + SM_LYB);
  float* lzB = (float*)(smem + SM_LZB);
  double* candA = (double*)(smem + SM_CANDA);
  double* candB = (double*)(smem + SM_CANDB);
  int* cselA = (int*)(smem + SM_CSELA);
  int* cselB = (int*)(smem + SM_CSELB);
  const int t = threadIdx.x;
  const float* pbA = pos + (size_t)b0 * NPC * 3;
  const float* pbB = pos + (size_t)(b0+1) * NPC * 3;
  const int entry  = (t >> 6) * 4 + ((t >> 4) & 3);   // wid*4 + row = 0..31
  const bool writer = ((t & 15) == 0);                // lane 0 of each row

  // Each thread owns 8 consecutive points of each cloud (idx t*8 .. t*8+7).
  float pxA[8], pyA[8], pzA[8], mindA[8];
  float pxB[8], pyB[8], pzB[8], mindB[8];
  int lo8[8];                            // loop-invariant key low words (shared)
  {
    const float4* srcA = (const float4*)(pbA + t * 24);
    const float4* srcB = (const float4*)(pbB + t * 24);
    float4 vA[6], vB[6];
    #pragma unroll
    for (int i = 0; i < 6; ++i) { vA[i] = srcA[i]; vB[i] = srcB[i]; }
    const float* fA = (const float*)vA;
    const float* fB = (const float*)vB;
    #pragma unroll
    for (int j = 0; j < 8; ++j) {
      pxA[j] = fA[3*j]; pyA[j] = fA[3*j+1]; pzA[j] = fA[3*j+2];
      pxB[j] = fB[3*j]; pyB[j] = fB[3*j+1]; pzB[j] = fB[3*j+2];
      lxA[t*8+j] = pxA[j]; lyA[t*8+j] = pyA[j]; lzA[t*8+j] = pzA[j];
      lxB[t*8+j] = pxB[j]; lyB[t*8+j] = pyB[j]; lzB[t*8+j] = pzB[j];
      lo8[j] = 4095 - (t*8 + j);         // larger lo == smaller idx
    }
  }
  __syncthreads();
  const float x0A = lxA[0], y0A = lyA[0], z0A = lzA[0];
  const float x0B = lxB[0], y0B = lyB[0], z0B = lzB[0];
  if (t == 0) { cselA[0] = 0; cselB[0] = 0; }

  // initial distances to point 0 + per-thread best keys (both clouds)
  double bkA, bkB;
  {
    double kA[4], kB[4];
    #pragma unroll
    for (int jp = 0; jp < 4; ++jp) {
      const int j0 = 2*jp, j1 = 2*jp + 1;
      float axd0 = pxA[j0]-x0A, ayd0 = pyA[j0]-y0A, azd0 = pzA[j0]-z0A;
      float axd1 = pxA[j1]-x0A, ayd1 = pyA[j1]-y0A, azd1 = pzA[j1]-z0A;
      float bxd0 = pxB[j0]-x0B, byd0 = pyB[j0]-y0B, bzd0 = pzB[j0]-z0B;
      float bxd1 = pxB[j1]-x0B, byd1 = pyB[j1]-y0B, bzd1 = pzB[j1]-z0B;
      float dA0 = (axd0*axd0 + ayd0*ayd0) + azd0*azd0;   // no-FMA: matches numpy
      float dA1 = (axd1*axd1 + ayd1*ayd1) + azd1*azd1;
      float dB0 = (bxd0*bxd0 + byd0*byd0) + bzd0*bzd0;
      float dB1 = (bxd1*bxd1 + byd1*byd1) + bzd1*bzd1;
      mindA[j0] = dA0; mindA[j1] = dA1;
      mindB[j0] = dB0; mindB[j1] = dB1;
      kA[jp] = dmax(pk(dA0, lo8[j0]), pk(dA1, lo8[j1]));
      kB[jp] = dmax(pk(dB0, lo8[j0]), pk(dB1, lo8[j1]));
    }
    bkA = dmax(dmax(kA[0], kA[1]), dmax(kA[2], kA[3]));
    bkB = dmax(dmax(kB[0], kB[1]), dmax(kB[2], kB[3]));
  }

  for (int s = 1; s < MPC; ++s) {
    // wave-level pre-reduce (both chains, independent -> interleaved by sched)
    double wA = rowmax16(bkA);
    double wB = rowmax16(bkB);
    const int ph = (s & 1) * 32;
    if (writer) { candA[ph + entry] = wA; candB[ph + entry] = wB; }
    __syncthreads();                     // the ONLY barrier per step
    double2 prA = ((const double2*)(candA + ph))[t & 15];
    double2 prB = ((const double2*)(candB + ph))[t & 15];
    double wA2 = rowmax16(dmax(prA.x, prA.y));
    double wB2 = rowmax16(dmax(prB.x, prB.y));
    const int selA = 4095 - pk_lo(wA2);
    const int selB = 4095 - pk_lo(wB2);
    const float sxA = lxA[selA], syA = lyA[selA], szA = lzA[selA];
    const float sxB = lxB[selB], syB = lyB[selB], szB = lzB[selB];
    if (t == 0) { cselA[s] = selA; cselB[s] = selB; }
    // distance updates (both clouds)
    double kA[4], kB[4];
    #pragma unroll
    for (int jp = 0; jp < 4; ++jp) {
      const int j0 = 2*jp, j1 = 2*jp + 1;
      float axd0 = pxA[j0]-sxA, ayd0 = pyA[j0]-syA, azd0 = pzA[j0]-szA;
      float axd1 = pxA[j1]-sxA, ayd1 = pyA[j1]-syA, azd1 = pzA[j1]-szA;
      float bxd0 = pxB[j0]-sxB, byd0 = pyB[j0]-syB, bzd0 = pzB[j0]-szB;
      float bxd1 = pxB[j1]-sxB, byd1 = pyB[j1]-syB, bzd1 = pzB[j1]-szB;
      float dA0 = (axd0*axd0 + ayd0*ayd0) + azd0*azd0;
      float dA1 = (axd1*axd1 + ayd1*ayd1) + azd1*azd1;
      float dB0 = (bxd0*bxd0 + byd0*byd0) + bzd0*bzd0;
      float dB1 = (bxd1*bxd1 + byd1*byd1) + bzd1*bzd1;
      float mA0 = fminf(mindA[j0], dA0), mA1 = fminf(mindA[j1], dA1);
      float mB0 = fminf(mindB[j0], dB0), mB1 = fminf(mindB[j1], dB1);
      mindA[j0] = mA0; mindA[j1] = mA1;
      mindB[j0] = mB0; mindB[j1] = mB1;
      kA[jp] = dmax(pk(mA0, lo8[j0]), pk(mA1, lo8[j1]));
      kB[jp] = dmax(pk(mB0, lo8[j0]), pk(mB1, lo8[j1]));
    }
    bkA = dmax(dmax(kA[0], kA[1]), dmax(kA[2], kA[3]));
    bkB = dmax(dmax(kB[0], kB[1]), dmax(kB[2], kB[3]));
  }
  __syncthreads();
  // coalesced output pass (coords re-read from LDS by selected index)
  for (int c = t; c < MPC; c += 512) {
    {
      const int il = cselA[c];
      const int cl = b0*MPC + c;
      const float X = lxA[il], Y = lyA[il], Z = lzA[il];
      centers[cl] = make_float4(X, Y, Z, 0.0f);
      out[OFF_SUBPOS + cl*3 + 0] = X;
      out[OFF_SUBPOS + cl*3 + 1] = Y;
      out[OFF_SUBPOS + cl*3 + 2] = Z;
      out[OFF_SUBB + cl] = (float)b0;
      out[OFF_IDCL + cl] = (float)(b0*NPC + il);
    }
    {
      const int il = cselB[c];
      const int cl = (b0+1)*MPC + c;
      const float X = lxB[il], Y = lyB[il], Z = lzB[il];
      centers[cl] = make_float4(X, Y, Z, 0.0f);
      out[OFF_SUBPOS + cl*3 + 0] = X;
      out[OFF_SUBPOS + cl*3 + 1] = Y;
      out[OFF_SUBPOS + cl*3 + 2] = Z;
      out[OFF_SUBB + cl] = (float)(b0+1);
      out[OFF_IDCL + cl] = (float)((b0+1)*NPC + il);
    }
  }
}

// ---------------- GEMM block (512 thr): h = x@W + b, plus BN sum/sumsq ------
__device__ void gemm_block(char* smem, const float* __restrict__ x,
                           const float* __restrict__ W, const float* __restrict__ bias,
                           float* __restrict__ h, float* __restrict__ stats, int blk)
{
  float (*xT)[68]  = (float(*)[68])(smem + SM_XT);   // [k][row], padded
  float (*Wl)[128] = (float(*)[128])(smem + SM_WL);
  float* bsum = (float*)(smem + SM_BS);
  float* bsq  = (float*)(smem + SM_BQ);
  const int t = threadIdx.x;
  const int row0 = blk * 64;
  if (t < 128) { bsum[t] = 0.0f; bsq[t] = 0.0f; }
  #pragma unroll
  for (int i = 0; i < 8; ++i) {
    const int idx = t + i*512;
    xT[idx & 63][idx >> 6] = x[(size_t)row0*64 + idx];
  }
  #pragma unroll
  for (int i = 0; i < 16; ++i) {
    const int idx = t + i*512;
    ((float*)Wl)[idx] = W[idx];
  }
  __syncthreads();
  const int tx = t & 31, ty = t >> 5;   // 32x16 threads, 4 rows x 4 cols each
  float acc[4][4] = {};
  #pragma unroll 8
  for (int k = 0; k < 64; ++k) {
    const float4 a  = *(const float4*)&xT[k][ty*4];
    const float4 b0 = *(const float4*)&Wl[k][tx*4];
    const float av[4] = {a.x, a.y, a.z, a.w};
    const float bw[4] = {b0.x, b0.y, b0.z, b0.w};
    #pragma unroll
    for (int i2 = 0; i2 < 4; ++i2)
      #pragma unroll
      for (int e = 0; e < 4; ++e)
        acc[i2][e] += av[i2] * bw[e];
  }
  const int c0 = tx*4;
  float bb[4];
  #pragma unroll
  for (int e = 0; e < 4; ++e) bb[e] = bias[c0+e];
  float s4[4] = {}, q4[4] = {};
  #pragma unroll
  for (int i2 = 0; i2 < 4; ++i2) {
    float vv[4];
    #pragma unroll
    for (int e = 0; e < 4; ++e) {
      float v = acc[i2][e] + bb[e];
      vv[e] = v; s4[e] += v; q4[e] += v*v;
    }
    const int r = row0 + ty*4 + i2;
    *(float4*)&h[(size_t)r*128 + c0] = make_float4(vv[0], vv[1], vv[2], vv[3]);
  }
  #pragma unroll
  for (int e = 0; e < 4; ++e) {
    atomicAdd(&bsum[c0+e], s4[e]);
    atomicAdd(&bsq[c0+e],  q4[e]);
  }
  __syncthreads();
  if (t < 128) {
    atomicAdd(&stats[t],      bsum[t]);
    atomicAdd(&stats[128+t],  bsq[t]);
  }
}

// ---------------- fused launcher kernel -------------------------------------
__global__ __launch_bounds__(512) void fused_fps_gemm(const float* __restrict__ pos,
                                                      float4* __restrict__ centers,
                                                      float* __restrict__ out,
                                                      const float* __restrict__ x,
                                                      const float* __restrict__ W,
                                                      const float* __restrict__ bias,
                                                      float* __restrict__ h,
                                                      float* __restrict__ stats)
{
  __shared__ __align__(16) char smem[SM_SIZE];
  if (blockIdx.x < NB/2) fps_block2(smem, pos, centers, out, blockIdx.x * 2);
  else                   gemm_block(smem, x, W, bias, h, stats, blockIdx.x - NB/2);
}

// ------- kNN + BN + pool fused: 512 blocks, 32 centers each -----------------
// kNN keys: f64 pack (d2 bits, idx); MIN key == lex (d2 asc, idx asc).
// Per-lane sorted-descending list L[0..15] (L[0] = worst): insert is 31 f64
// min/max ops, no rescan.
#define KBIG __hiloint2double(0x7f7fffff, 0xffffffff)
#define CD_STRIDE 17                     // pad: kill 32-way write conflicts

__global__ __launch_bounds__(256) void knn_pool(const float* __restrict__ pos,
                                                const float4* __restrict__ centers,
                                                const float* __restrict__ h,
                                                const float* __restrict__ aux,
                                                const float* __restrict__ stats,
                                                const float* __restrict__ gamma,
                                                const float* __restrict__ beta,
                                                float* __restrict__ out)
{
  #pragma clang fp contract(off)
  __shared__ float4 lp[NPC];        // 64KB; reused as candidate scratch after scan
  __shared__ float  scl[128], ssh[128];
  __shared__ int    fid[32][16];
  const int blk = blockIdx.x;       // 512 blocks; 32 per cloud
  const int b   = blk >> 5;
  const int c0  = (blk & 31) * 32;  // first local center of this block
  const int t   = threadIdx.x;
  const int q   = t & 7;            // subset
  const int cc  = t >> 3;           // center within block, 0..31
  // BN scale/shift (redundant per block; trivial)
  if (t < 128) {
    const float inv = 1.0f / 65536.0f;
    const float mu  = stats[t] * inv;
    const float var = stats[128+t] * inv - mu*mu;
    const float sc  = gamma[t] * rsqrtf(var + 1e-5f);
    scl[t] = sc;
    ssh[t] = beta[t] - mu*sc;
  }
  const float* pb = pos + (size_t)b * NPC * 3;
  for (int i = t; i < NPC; i += 256)
    lp[i] = make_float4(pb[3*i], pb[3*i+1], pb[3*i+2], 0.0f);
  __syncthreads();
  const int cg = b*MPC + c0 + cc;   // global cluster index
  const float4 C = centers[cg];
  double L[16];
  #pragma unroll
  for (int k = 0; k < 16; ++k) L[k] = KBIG;
  for (int jj = 0; jj < NPC/8; ++jj) {
    const int j = jj*8 + q;
    const float4 p = lp[j];
    float dx = C.x - p.x, dy = C.y - p.y, dz = C.z - p.z;
    float d2 = (dx*dx + dy*dy) + dz*dz;   // no-FMA
    double nk = pk(d2, j);
    if (nk < L[0]) {                      // beats current worst -> sorted insert
      #pragma unroll
      for (int k = 0; k < 15; ++k) L[k] = dmin(L[k], dmax(L[k+1], nk));
      L[15] = dmin(L[15], nk);
    }
  }
  __syncthreads();                  // pos data no longer needed
  double* cd = (double*)lp;         // [256 lanes][17-padded 16 keys] = 34816 B
  #pragma unroll
  for (int k = 0; k < 16; ++k) cd[t*CD_STRIDE + k] = L[k];
  __syncthreads();
  if (q == 0) {
    // merge 8 sorted sublists (128 keys) -> exact global top-16 set
    double M[16];
    #pragma unroll
    for (int k = 0; k < 16; ++k) M[k] = KBIG;
    for (int ss = 0; ss < 8; ++ss) {
      const double* src = cd + (cc*8 + ss)*CD_STRIDE;
      #pragma unroll
      for (int k = 0; k < 16; ++k) {
        double nk = src[k];
        if (nk < M[0]) {
          #pragma unroll
          for (int m = 0; m < 15; ++m) M[m] = dmin(M[m], dmax(M[m+1], nk));
          M[15] = dmin(M[15], nk);
        }
      }
    }
    #pragma unroll
    for (int k = 0; k < 16; ++k) fid[cc][k] = b*NPC + pk_lo(M[k]);
  }
  __syncthreads();
  // ---- pool: 16 passes, 2 clusters per pass (128 cols each) ----------------
  for (int g = 0; g < 16; ++g) {
    const int cc2 = g*2 + (t >> 7);        // 0..31
    const int col = t & 127;
    const int cl  = b*MPC + c0 + cc2;
    const float sc = scl[col], sh = ssh[col];
    float mv = 0.0f;                       // relu >= 0, so 0 == -inf here
    #pragma unroll
    for (int k = 0; k < 16; ++k) {
      const float hv = h[(size_t)fid[cc2][k]*128 + col];
      mv = fmaxf(mv, fmaxf(sc*hv + sh, 0.0f));
    }
    out[OFF_XOUT + (size_t)cl*128 + col] = mv;
    if (col < 32) {
      float s = 0.0f;
      #pragma unroll
      for (int k = 0; k < 16; ++k) s += aux[(size_t)fid[cc2][k]*32 + col];
      out[OFF_AUX + (size_t)cl*32 + col] = s * (1.0f/16.0f);
    }
  }
}

extern "C" void kernel_launch(void* const* d_in, const int* in_sizes, int n_in,
                              void* d_out, int out_size, void* d_ws, size_t ws_size,
                              hipStream_t stream)
{
  const float* x     = (const float*)d_in[0];
  const float* pos   = (const float*)d_in[1];
  // d_in[2] = batch (int32) — clouds are equal-size, derived analytically
  const float* aux   = (const float*)d_in[3];
  const float* W     = (const float*)d_in[4];
  const float* bias  = (const float*)d_in[5];
  const float* gamma = (const float*)d_in[6];
  const float* beta  = (const float*)d_in[7];
  float* out = (float*)d_out;
  char*  ws  = (char*)d_ws;
  if (ws_size < (size_t)WS_NEED) return;   // insufficient scratch: bail cleanly

  float*  h       = (float*)(ws + WS_H);
  float4* centers = (float4*)(ws + WS_CENTERS);
  float*  stats   = (float*)(ws + WS_STATS);

  hipMemsetAsync(stats, 0, 256*4, stream);  // BN accumulators: zero every call
  hipLaunchKernelGGL(fused_fps_gemm, dim3(NB/2 + PTOT/64), dim3(512), 0, stream,
                     pos, centers, out, x, W, bias, h, stats);
  hipLaunchKernelGGL(knn_pool, dim3(512), dim3(256), 0, stream,
                     pos, centers, h, aux, stats, gamma, beta, out);
}

// Round 11
// 743.401 us; speedup vs baseline: 1.6130x; 1.6130x over previous
//
#include <hip/hip_runtime.h>
#include <hip/hip_bf16.h>
#include <math.h>

#define NB    16
#define NPC   4096        // points per cloud
#define MPC   1024        // clusters per cloud
#define PTOT  65536
#define NCLU  16384
#define KNN_  16
#define CIN   64
#define COUT_ 128
#define CAUX_ 32

// out offsets (float elements), outputs concatenated in reference return order
#define OFF_XOUT   0
#define OFF_SUBPOS (NCLU*COUT_)               // 2097152
#define OFF_SUBB   (OFF_SUBPOS + NCLU*3)      // 2146304
#define OFF_AUX    (OFF_SUBB + NCLU)          // 2162688
#define OFF_IDCL   (OFF_AUX + NCLU*CAUX_)     // 2686976

// ws offsets (bytes)
#define WS_H        0
#define WS_CENTERS  (PTOT*COUT_*4)            // h: P x 128 f32
#define WS_STATS    (WS_CENTERS + NCLU*16)    // centers: float4 per cluster
#define WS_NEED     (WS_STATS + 256*4)

// ---- shared-memory overlay for the fused fps/gemm kernel (512 threads) -----
// fps view: cand = 2 parity halves x 32 f64 (one entry per 16-lane row)
#define SM_LX    0                      // 4096 f  (16384 B)
#define SM_LY    16384
#define SM_LZ    32768
#define SM_CAND  49152                  // 2 * 32 f64 = 512 B
#define SM_CSEL  49664                  // 1024 int = 4096 B -> 53760
// gemm view:
#define SM_XT    0                      // float[64][68] = 17408 B
#define SM_WL    17408                  // float[64][128] = 32768 B -> 50176
#define SM_BS    50176                  // float[128]
#define SM_BQ    50688                  // float[128] -> 51200
#define SM_SIZE  53760

// f64-packed keys: hi32 = f32 bits of d2 (>=0, finite -> positive f64, no NaN),
// lo32 = index payload. Positive doubles order exactly as their u64 bit
// patterns; f64 denormals are never flushed on AMD -> v_max_f64/v_min_f64 is a
// single-instruction lexicographic compare.
__device__ __forceinline__ double dmax(double a, double b) { return __builtin_fmax(a, b); }
__device__ __forceinline__ double dmin(double a, double b) { return __builtin_fmin(a, b); }
__device__ __forceinline__ double pk(float d, int lo) {
  return __hiloint2double(__float_as_int(d), lo);
}
__device__ __forceinline__ int pk_lo(double k) {
  return (int)(unsigned)(__double_as_longlong(k) & 0xFFFFFFFFll);
}

// DPP row_ror:N on an f64 (both 32b halves, same control -> consistent lanes).
template <int CTRL>
__device__ __forceinline__ double dpp64(double v) {
  long long u = __double_as_longlong(v);
  int lo = (int)(unsigned)(u & 0xFFFFFFFFll);
  int hi = (int)(unsigned)((unsigned long long)u >> 32);
  int rlo = __builtin_amdgcn_update_dpp(0, lo, CTRL, 0xf, 0xf, true);
  int rhi = __builtin_amdgcn_update_dpp(0, hi, CTRL, 0xf, 0xf, true);
  return __longlong_as_double(((long long)rhi << 32) | (long long)(unsigned)rlo);
}
#define ROR1 0x121
#define ROR2 0x122
#define ROR4 0x124
#define ROR8 0x128

// full 16-lane-row max via DPP rotate-accumulate (VALU pipe only)
__device__ __forceinline__ double rowmax16(double w) {
  w = dmax(w, dpp64<ROR1>(w));
  w = dmax(w, dpp64<ROR2>(w));
  w = dmax(w, dpp64<ROR4>(w));
  w = dmax(w, dpp64<ROR8>(w));
  return w;
}

// ---------------- FPS block: 512 thr, wave pre-reduce, 1 barrier/step -------
__device__ void fps_block(char* smem, const float* __restrict__ pos,
                          float4* __restrict__ centers, float* __restrict__ out)
{
  #pragma clang fp contract(off)
  float* lx = (float*)(smem + SM_LX);
  float* ly = (float*)(smem + SM_LY);
  float* lz = (float*)(smem + SM_LZ);
  double* cand = (double*)(smem + SM_CAND);
  int*   csel = (int*)(smem + SM_CSEL);
  const int b = blockIdx.x;
  const int t = threadIdx.x;
  const float* pb = pos + (size_t)b * NPC * 3;
  const int entry  = (t >> 6) * 4 + ((t >> 4) & 3);   // wid*4 + row = 0..31
  const bool writer = ((t & 15) == 0);                // lane 0 of each row

  // Each thread owns 8 consecutive points (in-cloud idx t*8 .. t*8+7).
  float px[8], py[8], pz[8], mind[8];
  int lo8[8];                            // loop-invariant key low words
  {
    const float4* src = (const float4*)(pb + t * 24);
    float4 v[6];
    #pragma unroll
    for (int i = 0; i < 6; ++i) v[i] = src[i];
    const float* f = (const float*)v;
    #pragma unroll
    for (int j = 0; j < 8; ++j) {
      px[j] = f[3*j]; py[j] = f[3*j+1]; pz[j] = f[3*j+2];
      lx[t*8+j] = px[j]; ly[t*8+j] = py[j]; lz[t*8+j] = pz[j];
      lo8[j] = 4095 - (t*8 + j);         // larger lo == smaller idx
    }
  }
  __syncthreads();
  const float x0 = lx[0], y0 = ly[0], z0 = lz[0];
  if (t == 0) csel[0] = 0;

  // initial distances to point 0 + per-thread best key
  double bk;
  {
    double k4[4];
    #pragma unroll
    for (int jp = 0; jp < 4; ++jp) {
      const int j0 = 2*jp, j1 = 2*jp + 1;
      float dx0 = px[j0]-x0, dy0 = py[j0]-y0, dz0 = pz[j0]-z0;
      float dx1 = px[j1]-x0, dy1 = py[j1]-y0, dz1 = pz[j1]-z0;
      float d0 = (dx0*dx0 + dy0*dy0) + dz0*dz0;   // no-FMA: matches numpy
      float d1 = (dx1*dx1 + dy1*dy1) + dz1*dz1;
      mind[j0] = d0; mind[j1] = d1;
      k4[jp] = dmax(pk(d0, lo8[j0]), pk(d1, lo8[j1]));
    }
    bk = dmax(dmax(k4[0], k4[1]), dmax(k4[2], k4[3]));
  }

  for (int s = 1; s < MPC; ++s) {
    // wave-level pre-reduce on VALU pipe; one f64 per 16-lane row to LDS
    double w = rowmax16(bk);
    const int ph = (s & 1) * 32;
    if (writer) cand[ph + entry] = w;
    __syncthreads();                     // the ONLY barrier per step
    // each lane reads one pair of the 32 row-winners (broadcast, 2-way banks)
    double2 pr = ((const double2*)(cand + ph))[t & 15];
    double w2 = rowmax16(dmax(pr.x, pr.y));
    const int sel = 4095 - pk_lo(w2);
    const float sx = lx[sel], sy = ly[sel], sz = lz[sel];  // broadcast reads
    if (t == 0) csel[s] = sel;
    // distance update + fresh per-thread best
    double k4[4];
    #pragma unroll
    for (int jp = 0; jp < 4; ++jp) {
      const int j0 = 2*jp, j1 = 2*jp + 1;
      float dx0 = px[j0]-sx, dy0 = py[j0]-sy, dz0 = pz[j0]-sz;
      float dx1 = px[j1]-sx, dy1 = py[j1]-sy, dz1 = pz[j1]-sz;
      float d0 = (dx0*dx0 + dy0*dy0) + dz0*dz0;
      float d1 = (dx1*dx1 + dy1*dy1) + dz1*dz1;
      float m0 = fminf(mind[j0], d0), m1 = fminf(mind[j1], d1);
      mind[j0] = m0; mind[j1] = m1;
      k4[jp] = dmax(pk(m0, lo8[j0]), pk(m1, lo8[j1]));
    }
    bk = dmax(dmax(k4[0], k4[1]), dmax(k4[2], k4[3]));
  }
  __syncthreads();
  // coalesced output pass (coords re-read from LDS by selected index)
  for (int c = t; c < MPC; c += 512) {
    const int il = csel[c];
    const int cl = b*MPC + c;
    const float X = lx[il], Y = ly[il], Z = lz[il];
    centers[cl] = make_float4(X, Y, Z, 0.0f);
    out[OFF_SUBPOS + cl*3 + 0] = X;
    out[OFF_SUBPOS + cl*3 + 1] = Y;
    out[OFF_SUBPOS + cl*3 + 2] = Z;
    out[OFF_SUBB + cl] = (float)b;
    out[OFF_IDCL + cl] = (float)(b*NPC + il);
  }
}

// ---------------- GEMM block (512 thr): h = x@W + b, plus BN sum/sumsq ------
__device__ void gemm_block(char* smem, const float* __restrict__ x,
                           const float* __restrict__ W, const float* __restrict__ bias,
                           float* __restrict__ h, float* __restrict__ stats, int blk)
{
  float (*xT)[68]  = (float(*)[68])(smem + SM_XT);   // [k][row], padded
  float (*Wl)[128] = (float(*)[128])(smem + SM_WL);
  float* bsum = (float*)(smem + SM_BS);
  float* bsq  = (float*)(smem + SM_BQ);
  const int t = threadIdx.x;
  const int row0 = blk * 64;
  if (t < 128) { bsum[t] = 0.0f; bsq[t] = 0.0f; }
  #pragma unroll
  for (int i = 0; i < 8; ++i) {
    const int idx = t + i*512;
    xT[idx & 63][idx >> 6] = x[(size_t)row0*64 + idx];
  }
  #pragma unroll
  for (int i = 0; i < 16; ++i) {
    const int idx = t + i*512;
    ((float*)Wl)[idx] = W[idx];
  }
  __syncthreads();
  const int tx = t & 31, ty = t >> 5;   // 32x16 threads, 4 rows x 4 cols each
  float acc[4][4] = {};
  #pragma unroll 8
  for (int k = 0; k < 64; ++k) {
    const float4 a  = *(const float4*)&xT[k][ty*4];
    const float4 b0 = *(const float4*)&Wl[k][tx*4];
    const float av[4] = {a.x, a.y, a.z, a.w};
    const float bw[4] = {b0.x, b0.y, b0.z, b0.w};
    #pragma unroll
    for (int i2 = 0; i2 < 4; ++i2)
      #pragma unroll
      for (int e = 0; e < 4; ++e)
        acc[i2][e] += av[i2] * bw[e];
  }
  const int c0 = tx*4;
  float bb[4];
  #pragma unroll
  for (int e = 0; e < 4; ++e) bb[e] = bias[c0+e];
  float s4[4] = {}, q4[4] = {};
  #pragma unroll
  for (int i2 = 0; i2 < 4; ++i2) {
    float vv[4];
    #pragma unroll
    for (int e = 0; e < 4; ++e) {
      float v = acc[i2][e] + bb[e];
      vv[e] = v; s4[e] += v; q4[e] += v*v;
    }
    const int r = row0 + ty*4 + i2;
    *(float4*)&h[(size_t)r*128 + c0] = make_float4(vv[0], vv[1], vv[2], vv[3]);
  }
  #pragma unroll
  for (int e = 0; e < 4; ++e) {
    atomicAdd(&bsum[c0+e], s4[e]);
    atomicAdd(&bsq[c0+e],  q4[e]);
  }
  __syncthreads();
  if (t < 128) {
    atomicAdd(&stats[t],      bsum[t]);
    atomicAdd(&stats[128+t],  bsq[t]);
  }
}

// ---------------- fused launcher kernel -------------------------------------
__global__ __launch_bounds__(512) void fused_fps_gemm(const float* __restrict__ pos,
                                                      float4* __restrict__ centers,
                                                      float* __restrict__ out,
                                                      const float* __restrict__ x,
                                                      const float* __restrict__ W,
                                                      const float* __restrict__ bias,
                                                      float* __restrict__ h,
                                                      float* __restrict__ stats)
{
  __shared__ __align__(16) char smem[SM_SIZE];
  if (blockIdx.x < NB) fps_block(smem, pos, centers, out);
  else                 gemm_block(smem, x, W, bias, h, stats, blockIdx.x - NB);
}

// ------- kNN + BN + pool fused: 512 blocks x 512 thr, 32 centers each -------
// kNN keys: f64 pack (d2 bits, idx); MIN key == lex (d2 asc, idx asc).
// Per-lane sorted-descending list L[0..15] (L[0] = worst): insert is 31 f64
// min/max ops, no rescan. 16 subsets per center; tree merge 16->4->1.
#define KBIG __hiloint2double(0x7f7fffff, 0xffffffff)
#define CD_STRIDE 17                     // pad: kill 32-way write conflicts

// knn_pool shared overlay (bytes)
#define KP_CD    0                      // 512 lanes * 17 f64 = 69632 (overlays lp 65536)
#define KP_SCL   69632                  // 128 f
#define KP_SSH   70144                  // 128 f
#define KP_FID   70656                  // 32*16 int = 2048 -> 72704
#define KP_SIZE  72704

__global__ __launch_bounds__(512) void knn_pool(const float* __restrict__ pos,
                                                const float4* __restrict__ centers,
                                                const float* __restrict__ h,
                                                const float* __restrict__ aux,
                                                const float* __restrict__ stats,
                                                const float* __restrict__ gamma,
                                                const float* __restrict__ beta,
                                                float* __restrict__ out)
{
  #pragma clang fp contract(off)
  __shared__ __align__(16) char sm2[KP_SIZE];
  float4* lp = (float4*)(sm2);          // [4096] pos cache; reused as cd after scan
  double* cd = (double*)(sm2 + KP_CD);
  float*  scl = (float*)(sm2 + KP_SCL);
  float*  ssh = (float*)(sm2 + KP_SSH);
  int*    fid = (int*)(sm2 + KP_FID);   // [32][16]
  // XCD-affinity swizzle (bijective, 512 % 8 == 0): each XCD owns 2 whole
  // clouds -> its pool-phase h-slice (2 x 2MB) fits the XCD's 4MB L2.
  const int vblk = ((blockIdx.x & 7) << 6) | (blockIdx.x >> 3);
  const int b   = vblk >> 5;
  const int c0  = (vblk & 31) * 32;     // first local center of this block
  const int t   = threadIdx.x;
  const int q   = t & 15;               // subset 0..15
  const int cc  = t >> 4;               // center within block, 0..31
  if (t < 128) {
    const float inv = 1.0f / 65536.0f;
    const float mu  = stats[t] * inv;
    const float var = stats[128+t] * inv - mu*mu;
    const float sc  = gamma[t] * rsqrtf(var + 1e-5f);
    scl[t] = sc;
    ssh[t] = beta[t] - mu*sc;
  }
  const float* pb = pos + (size_t)b * NPC * 3;
  for (int i = t; i < NPC; i += 512)
    lp[i] = make_float4(pb[3*i], pb[3*i+1], pb[3*i+2], 0.0f);
  __syncthreads();
  const float4 C = centers[b*MPC + c0 + cc];
  double L[16];
  #pragma unroll
  for (int k = 0; k < 16; ++k) L[k] = KBIG;
  for (int jj = 0; jj < NPC/16; ++jj) {
    const int j = jj*16 + q;            // strictly increasing within lane
    const float4 p = lp[j];
    float dx = C.x - p.x, dy = C.y - p.y, dz = C.z - p.z;
    float d2 = (dx*dx + dy*dy) + dz*dz; // no-FMA
    double nk = pk(d2, j);
    if (nk < L[0]) {                    // beats current worst -> sorted insert
      #pragma unroll
      for (int k = 0; k < 15; ++k) L[k] = dmin(L[k], dmax(L[k+1], nk));
      L[15] = dmin(L[15], nk);
    }
  }
  __syncthreads();                      // pos data no longer needed
  #pragma unroll
  for (int k = 0; k < 16; ++k) cd[t*CD_STRIDE + k] = L[k];
  __syncthreads();
  // round 1: lanes q<4 merge group {q, q+4, q+8, q+12} (own list in regs)
  if (q < 4) {
    #pragma unroll
    for (int r = 1; r <= 3; ++r) {
      const double* src = cd + (cc*16 + q + 4*r)*CD_STRIDE;
      #pragma unroll
      for (int k = 0; k < 16; ++k) {
        double nk = src[k];
        if (nk < L[0]) {
          #pragma unroll
          for (int m = 0; m < 15; ++m) L[m] = dmin(L[m], dmax(L[m+1], nk));
          L[15] = dmin(L[15], nk);
        }
      }
    }
    #pragma unroll
    for (int k = 0; k < 16; ++k) cd[t*CD_STRIDE + k] = L[k];
  }
  __syncthreads();
  // round 2: lane q==0 merges the 4 group winners -> exact global top-16
  if (q == 0) {
    #pragma unroll
    for (int r = 1; r <= 3; ++r) {
      const double* src = cd + (cc*16 + r)*CD_STRIDE;
      #pragma unroll
      for (int k = 0; k < 16; ++k) {
        double nk = src[k];
        if (nk < L[0]) {
          #pragma unroll
          for (int m = 0; m < 15; ++m) L[m] = dmin(L[m], dmax(L[m+1], nk));
          L[15] = dmin(L[15], nk);
        }
      }
    }
    #pragma unroll
    for (int k = 0; k < 16; ++k) fid[cc*16 + k] = b*NPC + pk_lo(L[k]);
  }
  __syncthreads();
  // ---- pool: 8 passes, 4 clusters per pass (128 cols each) -----------------
  for (int g = 0; g < 8; ++g) {
    const int cc2 = g*4 + (t >> 7);     // 0..31
    const int col = t & 127;
    const int cl  = b*MPC + c0 + cc2;
    const float sc = scl[col], sh = ssh[col];
    float mv = 0.0f;                    // relu >= 0, so 0 == -inf here
    #pragma unroll
    for (int k = 0; k < 16; ++k) {
      const float hv = h[(size_t)fid[cc2*16 + k]*128 + col];
      mv = fmaxf(mv, fmaxf(sc*hv + sh, 0.0f));
    }
    out[OFF_XOUT + (size_t)cl*128 + col] = mv;
    if (col < 32) {
      float s = 0.0f;
      #pragma unroll
      for (int k = 0; k < 16; ++k) s += aux[(size_t)fid[cc2*16 + k]*32 + col];
      out[OFF_AUX + (size_t)cl*32 + col] = s * (1.0f/16.0f);
    }
  }
}

extern "C" void kernel_launch(void* const* d_in, const int* in_sizes, int n_in,
                              void* d_out, int out_size, void* d_ws, size_t ws_size,
                              hipStream_t stream)
{
  const float* x     = (const float*)d_in[0];
  const float* pos   = (const float*)d_in[1];
  // d_in[2] = batch (int32) — clouds are equal-size, derived analytically
  const float* aux   = (const float*)d_in[3];
  const float* W     = (const float*)d_in[4];
  const float* bias  = (const float*)d_in[5];
  const float* gamma = (const float*)d_in[6];
  const float* beta  = (const float*)d_in[7];
  float* out = (float*)d_out;
  char*  ws  = (char*)d_ws;
  if (ws_size < (size_t)WS_NEED) return;   // insufficient scratch: bail cleanly

  float*  h       = (float*)(ws + WS_H);
  float4* centers = (float4*)(ws + WS_CENTERS);
  float*  stats   = (float*)(ws + WS_STATS);

  hipMemsetAsync(stats, 0, 256*4, stream);  // BN accumulators: zero every call
  hipLaunchKernelGGL(fused_fps_gemm, dim3(NB + PTOT/64), dim3(512), 0, stream,
                     pos, centers, out, x, W, bias, h, stats);
  hipLaunchKernelGGL(knn_pool, dim3(512), dim3(512), 0, stream,
                     pos, centers, h, aux, stats, gamma, beta, out);
}

// Round 12
// 733.420 us; speedup vs baseline: 1.6350x; 1.0136x over previous
//
#include <hip/hip_runtime.h>
#include <hip/hip_bf16.h>
#include <math.h>

#define NB    16
#define NPC   4096        // points per cloud
#define MPC   1024        // clusters per cloud
#define PTOT  65536
#define NCLU  16384
#define KNN_  16
#define CIN   64
#define COUT_ 128
#define CAUX_ 32

// out offsets (float elements), outputs concatenated in reference return order
#define OFF_XOUT   0
#define OFF_SUBPOS (NCLU*COUT_)               // 2097152
#define OFF_SUBB   (OFF_SUBPOS + NCLU*3)      // 2146304
#define OFF_AUX    (OFF_SUBB + NCLU)          // 2162688
#define OFF_IDCL   (OFF_AUX + NCLU*CAUX_)     // 2686976

// ws offsets (bytes)
#define WS_H        0
#define WS_CENTERS  (PTOT*COUT_*4)            // h: P x 128 f32
#define WS_STATS    (WS_CENTERS + NCLU*16)    // centers: float4 per cluster
#define WS_NEED     (WS_STATS + 256*4)

// ---- shared-memory overlay for the fused fps/gemm kernel (512 threads) -----
#define SM_LX    0                      // 4096 f  (16384 B)
#define SM_LY    16384
#define SM_LZ    32768
#define SM_CAND  49152                  // 2 * 32 f64 = 512 B
#define SM_CSEL  49664                  // 1024 int = 4096 B -> 53760
#define SM_SIDX  53760                  // 4096 int = 16384 B -> 70144
#define SM_HIST  70144                  // 512 int = 2048 B (bbox scratch overlays)
#define SM_SCANA 72192                  // 512 int
#define SM_SCANB 74240                  // 512 int -> 76288
// gemm view:
#define SM_XT    0                      // float[64][68] = 17408 B
#define SM_WL    17408                  // float[64][128] = 32768 B -> 50176
#define SM_BS    50176                  // float[128]
#define SM_BQ    50688                  // float[128] -> 51200
#define SM_SIZE  76288

// f64-packed keys: hi32 = f32 bits of d2 (>=0, finite -> positive f64, no NaN),
// lo32 = index payload. Positive doubles order exactly as their u64 bit
// patterns; f64 denormals are never flushed on AMD -> v_max_f64/v_min_f64 is a
// single-instruction lexicographic compare.
__device__ __forceinline__ double dmax(double a, double b) { return __builtin_fmax(a, b); }
__device__ __forceinline__ double dmin(double a, double b) { return __builtin_fmin(a, b); }
__device__ __forceinline__ double pk(float d, int lo) {
  return __hiloint2double(__float_as_int(d), lo);
}
__device__ __forceinline__ int pk_lo(double k) {
  return (int)(unsigned)(__double_as_longlong(k) & 0xFFFFFFFFll);
}

// DPP row_ror:N (rotate within 16-lane row; all source lanes valid).
template <int CTRL>
__device__ __forceinline__ double dpp64(double v) {
  long long u = __double_as_longlong(v);
  int lo = (int)(unsigned)(u & 0xFFFFFFFFll);
  int hi = (int)(unsigned)((unsigned long long)u >> 32);
  int rlo = __builtin_amdgcn_update_dpp(0, lo, CTRL, 0xf, 0xf, true);
  int rhi = __builtin_amdgcn_update_dpp(0, hi, CTRL, 0xf, 0xf, true);
  return __longlong_as_double(((long long)rhi << 32) | (long long)(unsigned)rlo);
}
template <int CTRL>
__device__ __forceinline__ float dpp32(float x) {
  return __int_as_float(__builtin_amdgcn_update_dpp(0, __float_as_int(x), CTRL, 0xf, 0xf, true));
}
#define ROR1 0x121
#define ROR2 0x122
#define ROR4 0x124
#define ROR8 0x128

__device__ __forceinline__ double rowmax16(double w) {
  w = dmax(w, dpp64<ROR1>(w));
  w = dmax(w, dpp64<ROR2>(w));
  w = dmax(w, dpp64<ROR4>(w));
  w = dmax(w, dpp64<ROR8>(w));
  return w;
}
__device__ __forceinline__ float row16maxf(float m) {
  m = fmaxf(m, dpp32<ROR1>(m));
  m = fmaxf(m, dpp32<ROR2>(m));
  m = fmaxf(m, dpp32<ROR4>(m));
  m = fmaxf(m, dpp32<ROR8>(m));
  return m;
}
__device__ __forceinline__ float row16minf(float m) {
  m = fminf(m, dpp32<ROR1>(m));
  m = fminf(m, dpp32<ROR2>(m));
  m = fminf(m, dpp32<ROR4>(m));
  m = fminf(m, dpp32<ROR8>(m));
  return m;
}

// 9-bit Morton code from 3x3-bit cell coords
__device__ __forceinline__ int mort3(int x, int y, int z) {
  int m = 0;
  #pragma unroll
  for (int bb = 0; bb < 3; ++bb)
    m |= (((x >> bb) & 1) << (3*bb + 2)) | (((y >> bb) & 1) << (3*bb + 1)) |
         (((z >> bb) & 1) << (3*bb));
  return m;
}

// ---------------- FPS block: Morton-sorted ownership + bbox pruning ---------
// Ownership is output-invariant: a group update is skipped only when it is
// PROVEN that fminf(mind,d)==mind for every owned point, so each point's mind
// trajectory (and hence the argmax sequence) is identical to the unpruned run.
__device__ void fps_block(char* smem, const float* __restrict__ pos,
                          float4* __restrict__ centers, float* __restrict__ out)
{
  #pragma clang fp contract(off)
  float* lx = (float*)(smem + SM_LX);
  float* ly = (float*)(smem + SM_LY);
  float* lz = (float*)(smem + SM_LZ);
  double* cand = (double*)(smem + SM_CAND);
  int*   csel = (int*)(smem + SM_CSEL);
  int*   sidx = (int*)(smem + SM_SIDX);
  int*   hist = (int*)(smem + SM_HIST);
  float* bbs  = (float*)(smem + SM_HIST);   // bbox scratch overlays hist
  int*   sA   = (int*)(smem + SM_SCANA);
  int*   sB   = (int*)(smem + SM_SCANB);
  const int b = blockIdx.x;
  const int t = threadIdx.x;
  const float* pb = pos + (size_t)b * NPC * 3;
  const int entry  = (t >> 6) * 4 + ((t >> 4) & 3);   // wid*4 + row = 0..31
  const bool writer = ((t & 15) == 0);                // lane 0 of each row

  // ---- load 8 consecutive original points; fill LDS coords -----------------
  float ox[8], oy[8], oz[8];
  {
    const float4* src = (const float4*)(pb + t * 24);
    float4 v[6];
    #pragma unroll
    for (int i = 0; i < 6; ++i) v[i] = src[i];
    const float* f = (const float*)v;
    #pragma unroll
    for (int j = 0; j < 8; ++j) {
      ox[j] = f[3*j]; oy[j] = f[3*j+1]; oz[j] = f[3*j+2];
      lx[t*8+j] = ox[j]; ly[t*8+j] = oy[j]; lz[t*8+j] = oz[j];
    }
  }
  // ---- cloud bbox (performance-only; any value is correct) -----------------
  float mnx = ox[0], mxx = ox[0], mny = oy[0], mxy = oy[0], mnz = oz[0], mxz = oz[0];
  #pragma unroll
  for (int j = 1; j < 8; ++j) {
    mnx = fminf(mnx, ox[j]); mxx = fmaxf(mxx, ox[j]);
    mny = fminf(mny, oy[j]); mxy = fmaxf(mxy, oy[j]);
    mnz = fminf(mnz, oz[j]); mxz = fmaxf(mxz, oz[j]);
  }
  mnx = row16minf(mnx); mxx = row16maxf(mxx);
  mny = row16minf(mny); mxy = row16maxf(mxy);
  mnz = row16minf(mnz); mxz = row16maxf(mxz);
  if (writer) {
    bbs[entry] = mnx; bbs[32+entry] = mxx; bbs[64+entry]  = mny;
    bbs[96+entry] = mxy; bbs[128+entry] = mnz; bbs[160+entry] = mxz;
  }
  __syncthreads();
  float gx0 = bbs[0], gx1 = bbs[32], gy0 = bbs[64], gy1 = bbs[96], gz0 = bbs[128], gz1 = bbs[160];
  #pragma unroll 8
  for (int w = 1; w < 32; ++w) {
    gx0 = fminf(gx0, bbs[w]);     gx1 = fmaxf(gx1, bbs[32+w]);
    gy0 = fminf(gy0, bbs[64+w]);  gy1 = fmaxf(gy1, bbs[96+w]);
    gz0 = fminf(gz0, bbs[128+w]); gz1 = fmaxf(gz1, bbs[160+w]);
  }
  __syncthreads();                       // bbox reads done before hist zeroing
  hist[t] = 0;
  __syncthreads();
  // ---- Morton keys + histogram ---------------------------------------------
  const float scx = 8.0f / ((gx1 - gx0) + 1e-6f);
  const float scy = 8.0f / ((gy1 - gy0) + 1e-6f);
  const float scz = 8.0f / ((gz1 - gz0) + 1e-6f);
  int key[8];
  #pragma unroll
  for (int j = 0; j < 8; ++j) {
    int cx = min(7, max(0, (int)((ox[j] - gx0) * scx)));
    int cy = min(7, max(0, (int)((oy[j] - gy0) * scy)));
    int cz = min(7, max(0, (int)((oz[j] - gz0) * scz)));
    key[j] = mort3(cx, cy, cz);
    atomicAdd(&hist[key[j]], 1);
  }
  __syncthreads();
  // ---- inclusive scan (Hillis-Steele) -> exclusive cursor ------------------
  const int hv = hist[t];
  sA[t] = hv;
  __syncthreads();
  for (int off = 1; off < 512; off <<= 1) {
    const int o = (t >= off) ? sA[t - off] : 0;
    __syncthreads();
    sA[t] += o;
    __syncthreads();
  }
  sB[t] = sA[t] - hv;                    // exclusive base == scatter cursor
  __syncthreads();
  #pragma unroll
  for (int j = 0; j < 8; ++j) {
    const int slot = atomicAdd(&sB[key[j]], 1);
    sidx[slot] = t*8 + j;
  }
  __syncthreads();
  // ---- re-own: 8 spatially coherent points + group bbox --------------------
  float px[8], py[8], pz[8], mind[8];
  int lo8[8];
  float bxn = 1e30f, bxx = -1e30f, byn = 1e30f, byy = -1e30f, bzn = 1e30f, bzz = -1e30f;
  #pragma unroll
  for (int j = 0; j < 8; ++j) {
    const int sid = sidx[t*8 + j];
    px[j] = lx[sid]; py[j] = ly[sid]; pz[j] = lz[sid];
    lo8[j] = 4095 - sid;                 // larger lo == smaller idx
    bxn = fminf(bxn, px[j]); bxx = fmaxf(bxx, px[j]);
    byn = fminf(byn, py[j]); byy = fmaxf(byy, py[j]);
    bzn = fminf(bzn, pz[j]); bzz = fmaxf(bzz, pz[j]);
  }
  const float x0 = lx[0], y0 = ly[0], z0 = lz[0];
  if (t == 0) csel[0] = 0;

  // ---- initial distances to point 0 + per-thread best key ------------------
  double bk;
  {
    double k4[4];
    #pragma unroll
    for (int jp = 0; jp < 4; ++jp) {
      const int j0 = 2*jp, j1 = 2*jp + 1;
      float dx0 = px[j0]-x0, dy0 = py[j0]-y0, dz0 = pz[j0]-z0;
      float dx1 = px[j1]-x0, dy1 = py[j1]-y0, dz1 = pz[j1]-z0;
      float d0 = (dx0*dx0 + dy0*dy0) + dz0*dz0;   // no-FMA: matches numpy
      float d1 = (dx1*dx1 + dy1*dy1) + dz1*dz1;
      mind[j0] = d0; mind[j1] = d1;
      k4[jp] = dmax(pk(d0, lo8[j0]), pk(d1, lo8[j1]));
    }
    bk = dmax(dmax(k4[0], k4[1]), dmax(k4[2], k4[3]));
  }

  for (int s = 1; s < MPC; ++s) {
    double w = rowmax16(bk);
    const int ph = (s & 1) * 32;
    if (writer) cand[ph + entry] = w;
    __syncthreads();                     // the ONLY barrier per step
    double2 pr = ((const double2*)(cand + ph))[t & 15];
    double w2 = rowmax16(dmax(pr.x, pr.y));
    const int sel = 4095 - pk_lo(w2);
    const float sx = lx[sel], sy = ly[sel], sz = lz[sel];  // broadcast reads
    if (t == 0) csel[s] = sel;
    // ---- bbox prune: skip iff PROVEN min_j d(sel,pj) >= max_j mind[j] ------
    const float bkhi = __int_as_float(__double2hiint(bk));  // = max_j mind[j]
    const float cxd = fmaxf(fmaxf(bxn - sx, sx - bxx), 0.0f);
    const float cyd = fmaxf(fmaxf(byn - sy, sy - byy), 0.0f);
    const float czd = fmaxf(fmaxf(bzn - sz, sz - bzz), 0.0f);
    const float lb = 0.99f * ((cxd*cxd + cyd*cyd) + czd*czd);  // safe lower bd
    if (lb < bkhi) {
      double k4[4];
      #pragma unroll
      for (int jp = 0; jp < 4; ++jp) {
        const int j0 = 2*jp, j1 = 2*jp + 1;
        float dx0 = px[j0]-sx, dy0 = py[j0]-sy, dz0 = pz[j0]-sz;
        float dx1 = px[j1]-sx, dy1 = py[j1]-sy, dz1 = pz[j1]-sz;
        float d0 = (dx0*dx0 + dy0*dy0) + dz0*dz0;
        float d1 = (dx1*dx1 + dy1*dy1) + dz1*dz1;
        float m0 = fminf(mind[j0], d0), m1 = fminf(mind[j1], d1);
        mind[j0] = m0; mind[j1] = m1;
        k4[jp] = dmax(pk(m0, lo8[j0]), pk(m1, lo8[j1]));
      }
      bk = dmax(dmax(k4[0], k4[1]), dmax(k4[2], k4[3]));
    }
  }
  __syncthreads();
  // ---- coalesced output pass -----------------------------------------------
  for (int c = t; c < MPC; c += 512) {
    const int il = csel[c];
    const int cl = b*MPC + c;
    const float X = lx[il], Y = ly[il], Z = lz[il];
    centers[cl] = make_float4(X, Y, Z, 0.0f);
    out[OFF_SUBPOS + cl*3 + 0] = X;
    out[OFF_SUBPOS + cl*3 + 1] = Y;
    out[OFF_SUBPOS + cl*3 + 2] = Z;
    out[OFF_SUBB + cl] = (float)b;
    out[OFF_IDCL + cl] = (float)(b*NPC + il);
  }
}

// ---------------- GEMM block (512 thr): h = x@W + b, plus BN sum/sumsq ------
__device__ void gemm_block(char* smem, const float* __restrict__ x,
                           const float* __restrict__ W, const float* __restrict__ bias,
                           float* __restrict__ h, float* __restrict__ stats, int blk)
{
  float (*xT)[68]  = (float(*)[68])(smem + SM_XT);   // [k][row], padded
  float (*Wl)[128] = (float(*)[128])(smem + SM_WL);
  float* bsum = (float*)(smem + SM_BS);
  float* bsq  = (float*)(smem + SM_BQ);
  const int t = threadIdx.x;
  const int row0 = blk * 64;
  if (t < 128) { bsum[t] = 0.0f; bsq[t] = 0.0f; }
  #pragma unroll
  for (int i = 0; i < 8; ++i) {
    const int idx = t + i*512;
    xT[idx & 63][idx >> 6] = x[(size_t)row0*64 + idx];
  }
  #pragma unroll
  for (int i = 0; i < 16; ++i) {
    const int idx = t + i*512;
    ((float*)Wl)[idx] = W[idx];
  }
  __syncthreads();
  const int tx = t & 31, ty = t >> 5;   // 32x16 threads, 4 rows x 4 cols each
  float acc[4][4] = {};
  #pragma unroll 8
  for (int k = 0; k < 64; ++k) {
    const float4 a  = *(const float4*)&xT[k][ty*4];
    const float4 b0 = *(const float4*)&Wl[k][tx*4];
    const float av[4] = {a.x, a.y, a.z, a.w};
    const float bw[4] = {b0.x, b0.y, b0.z, b0.w};
    #pragma unroll
    for (int i2 = 0; i2 < 4; ++i2)
      #pragma unroll
      for (int e = 0; e < 4; ++e)
        acc[i2][e] += av[i2] * bw[e];
  }
  const int c0 = tx*4;
  float bb[4];
  #pragma unroll
  for (int e = 0; e < 4; ++e) bb[e] = bias[c0+e];
  float s4[4] = {}, q4[4] = {};
  #pragma unroll
  for (int i2 = 0; i2 < 4; ++i2) {
    float vv[4];
    #pragma unroll
    for (int e = 0; e < 4; ++e) {
      float v = acc[i2][e] + bb[e];
      vv[e] = v; s4[e] += v; q4[e] += v*v;
    }
    const int r = row0 + ty*4 + i2;
    *(float4*)&h[(size_t)r*128 + c0] = make_float4(vv[0], vv[1], vv[2], vv[3]);
  }
  #pragma unroll
  for (int e = 0; e < 4; ++e) {
    atomicAdd(&bsum[c0+e], s4[e]);
    atomicAdd(&bsq[c0+e],  q4[e]);
  }
  __syncthreads();
  if (t < 128) {
    atomicAdd(&stats[t],      bsum[t]);
    atomicAdd(&stats[128+t],  bsq[t]);
  }
}

// ---------------- fused launcher kernel -------------------------------------
__global__ __launch_bounds__(512) void fused_fps_gemm(const float* __restrict__ pos,
                                                      float4* __restrict__ centers,
                                                      float* __restrict__ out,
                                                      const float* __restrict__ x,
                                                      const float* __restrict__ W,
                                                      const float* __restrict__ bias,
                                                      float* __restrict__ h,
                                                      float* __restrict__ stats)
{
  __shared__ __align__(16) char smem[SM_SIZE];
  if (blockIdx.x < NB) fps_block(smem, pos, centers, out);
  else                 gemm_block(smem, x, W, bias, h, stats, blockIdx.x - NB);
}

// ------- kNN + BN + pool fused: 512 blocks x 512 thr, 32 centers each -------
#define KBIG __hiloint2double(0x7f7fffff, 0xffffffff)
#define CD_STRIDE 17                     // pad: kill 32-way write conflicts

// knn_pool shared overlay (bytes)
#define KP_CD    0                      // 512 lanes * 17 f64 = 69632 (overlays lp 65536)
#define KP_SCL   69632                  // 128 f
#define KP_SSH   70144                  // 128 f
#define KP_FID   70656                  // 32*16 int = 2048 -> 72704
#define KP_SIZE  72704

__global__ __launch_bounds__(512) void knn_pool(const float* __restrict__ pos,
                                                const float4* __restrict__ centers,
                                                const float* __restrict__ h,
                                                const float* __restrict__ aux,
                                                const float* __restrict__ stats,
                                                const float* __restrict__ gamma,
                                                const float* __restrict__ beta,
                                                float* __restrict__ out)
{
  #pragma clang fp contract(off)
  __shared__ __align__(16) char sm2[KP_SIZE];
  float4* lp = (float4*)(sm2);          // [4096] pos cache; reused as cd after scan
  double* cd = (double*)(sm2 + KP_CD);
  float*  scl = (float*)(sm2 + KP_SCL);
  float*  ssh = (float*)(sm2 + KP_SSH);
  int*    fid = (int*)(sm2 + KP_FID);   // [32][16]
  // XCD-affinity swizzle (bijective, 512 % 8 == 0): each XCD owns 2 whole
  // clouds -> its pool-phase h-slice (2 x 2MB) fits the XCD's 4MB L2.
  const int vblk = ((blockIdx.x & 7) << 6) | (blockIdx.x >> 3);
  const int b   = vblk >> 5;
  const int c0  = (vblk & 31) * 32;     // first local center of this block
  const int t   = threadIdx.x;
  const int q   = t & 15;               // subset 0..15
  const int cc  = t >> 4;               // center within block, 0..31
  if (t < 128) {
    const float inv = 1.0f / 65536.0f;
    const float mu  = stats[t] * inv;
    const float var = stats[128+t] * inv - mu*mu;
    const float sc  = gamma[t] * rsqrtf(var + 1e-5f);
    scl[t] = sc;
    ssh[t] = beta[t] - mu*sc;
  }
  const float* pb = pos + (size_t)b * NPC * 3;
  for (int i = t; i < NPC; i += 512)
    lp[i] = make_float4(pb[3*i], pb[3*i+1], pb[3*i+2], 0.0f);
  __syncthreads();
  const float4 C = centers[b*MPC + c0 + cc];
  double L[16];
  #pragma unroll
  for (int k = 0; k < 16; ++k) L[k] = KBIG;
  for (int jj = 0; jj < NPC/16; ++jj) {
    const int j = jj*16 + q;            // strictly increasing within lane
    const float4 p = lp[j];
    float dx = C.x - p.x, dy = C.y - p.y, dz = C.z - p.z;
    float d2 = (dx*dx + dy*dy) + dz*dz; // no-FMA
    double nk = pk(d2, j);
    if (nk < L[0]) {                    // beats current worst -> sorted insert
      #pragma unroll
      for (int k = 0; k < 15; ++k) L[k] = dmin(L[k], dmax(L[k+1], nk));
      L[15] = dmin(L[15], nk);
    }
  }
  __syncthreads();                      // pos data no longer needed
  #pragma unroll
  for (int k = 0; k < 16; ++k) cd[t*CD_STRIDE + k] = L[k];
  __syncthreads();
  // round 1: lanes q<4 merge group {q, q+4, q+8, q+12} (own list in regs)
  if (q < 4) {
    #pragma unroll
    for (int r = 1; r <= 3; ++r) {
      const double* src = cd + (cc*16 + q + 4*r)*CD_STRIDE;
      #pragma unroll
      for (int k = 0; k < 16; ++k) {
        double nk = src[k];
        if (nk < L[0]) {
          #pragma unroll
          for (int m = 0; m < 15; ++m) L[m] = dmin(L[m], dmax(L[m+1], nk));
          L[15] = dmin(L[15], nk);
        }
      }
    }
    #pragma unroll
    for (int k = 0; k < 16; ++k) cd[t*CD_STRIDE + k] = L[k];
  }
  __syncthreads();
  // round 2: lane q==0 merges the 4 group winners -> exact global top-16
  if (q == 0) {
    #pragma unroll
    for (int r = 1; r <= 3; ++r) {
      const double* src = cd + (cc*16 + r)*CD_STRIDE;
      #pragma unroll
      for (int k = 0; k < 16; ++k) {
        double nk = src[k];
        if (nk < L[0]) {
          #pragma unroll
          for (int m = 0; m < 15; ++m) L[m] = dmin(L[m], dmax(L[m+1], nk));
          L[15] = dmin(L[15], nk);
        }
      }
    }
    #pragma unroll
    for (int k = 0; k < 16; ++k) fid[cc*16 + k] = b*NPC + pk_lo(L[k]);
  }
  __syncthreads();
  // ---- pool: 8 passes, 4 clusters per pass (128 cols each) -----------------
  for (int g = 0; g < 8; ++g) {
    const int cc2 = g*4 + (t >> 7);     // 0..31
    const int col = t & 127;
    const int cl  = b*MPC + c0 + cc2;
    const float sc = scl[col], sh = ssh[col];
    float mv = 0.0f;                    // relu >= 0, so 0 == -inf here
    #pragma unroll
    for (int k = 0; k < 16; ++k) {
      const float hv = h[(size_t)fid[cc2*16 + k]*128 + col];
      mv = fmaxf(mv, fmaxf(sc*hv + sh, 0.0f));
    }
    out[OFF_XOUT + (size_t)cl*128 + col] = mv;
    if (col < 32) {
      float s = 0.0f;
      #pragma unroll
      for (int k = 0; k < 16; ++k) s += aux[(size_t)fid[cc2*16 + k]*32 + col];
      out[OFF_AUX + (size_t)cl*32 + col] = s * (1.0f/16.0f);
    }
  }
}

extern "C" void kernel_launch(void* const* d_in, const int* in_sizes, int n_in,
                              void* d_out, int out_size, void* d_ws, size_t ws_size,
                              hipStream_t stream)
{
  const float* x     = (const float*)d_in[0];
  const float* pos   = (const float*)d_in[1];
  // d_in[2] = batch (int32) — clouds are equal-size, derived analytically
  const float* aux   = (const float*)d_in[3];
  const float* W     = (const float*)d_in[4];
  const float* bias  = (const float*)d_in[5];
  const float* gamma = (const float*)d_in[6];
  const float* beta  = (const float*)d_in[7];
  float* out = (float*)d_out;
  char*  ws  = (char*)d_ws;
  if (ws_size < (size_t)WS_NEED) return;   // insufficient scratch: bail cleanly

  float*  h       = (float*)(ws + WS_H);
  float4* centers = (float4*)(ws + WS_CENTERS);
  float*  stats   = (float*)(ws + WS_STATS);

  hipMemsetAsync(stats, 0, 256*4, stream);  // BN accumulators: zero every call
  hipLaunchKernelGGL(fused_fps_gemm, dim3(NB + PTOT/64), dim3(512), 0, stream,
                     pos, centers, out, x, W, bias, h, stats);
  hipLaunchKernelGGL(knn_pool, dim3(512), dim3(512), 0, stream,
                     pos, centers, h, aux, stats, gamma, beta, out);
}